// Round 2
// baseline (122.681 us; speedup 1.0000x reference)
//
#include <hip/hip_runtime.h>
#include <math.h>

// Quantized softmax over axis 1 of x(8, 4096, 1024) fp32.
// Groups: g = b*1024 + c (8192 groups of 4096, stride 1024 floats).
//
// Key structural idea: after input fake-quant, x is fully determined by its
// int8 code q = clip(rint(x/s), -128, 127); xq = q*s exactly. Pass 1 emits a
// 32 MiB int8 code tensor; passes 2/3 read codes (L2/L3-resident) instead of
// re-reading the 128 MiB fp32 input. Arithmetic is bit-identical.

static constexpr int Bdim = 8;
static constexpr int Jdim = 4096;
static constexpr int Cdim = 1024;
static constexpr int JCHUNK = 64;                 // rows per block chunk
static constexpr int NJC = Jdim / JCHUNK;         // 64
static constexpr int NG = Bdim * Cdim;            // 8192 groups
static constexpr int PSIZE = Bdim * NJC * Cdim;   // 524288 partials
static constexpr size_t CODES_BYTES = (size_t)Bdim * Jdim * Cdim;  // 32 MiB

// float-region layout (offsets in floats, region starts after codes if used)
static constexpr int SC_OFF   = 0;                // [0]=amax_sub [1]=max_s [2]=min_s
static constexpr int GMAX_OFF = 16;               // 8192 group max CODES (as float)
static constexpr int S_OFF    = GMAX_OFF + NG;    // 8192 group sums of e_q
static constexpr int A_OFF    = S_OFF + NG;       // pmax codes / partial sums
static constexpr int B_OFF    = A_OFF + PSIZE;    // pmin codes
static constexpr size_t FREGION_BYTES = ((size_t)B_OFF + PSIZE) * 4;  // ~4.26 MB

__device__ __forceinline__ float code8(float x, float sinv) {
    // int8 code as float; rintf = round-half-even matches jnp.round
    return fminf(fmaxf(rintf(x * sinv), -128.0f), 127.0f);
}

// e_q = fq16(exp(fq16(clip(xq - gmax, -12, 0)))); scale_e = 1/32767 exactly
// (group-max element has sub==0 -> e==1 -> absmax(e)==1).
__device__ __forceinline__ float eq_from(float xq, float gmv, float ssub_inv, float ssub) {
    float sub = fminf(fmaxf(xq - gmv, -12.0f), 0.0f);
    float q   = fminf(fmaxf(rintf(sub * ssub_inv), -32768.0f), 32767.0f);
    float e   = __expf(q * ssub);
    return rintf(e * 32767.0f) * (1.0f / 32767.0f);
}

// Pass 1: read x, (optionally) write int8 codes, write per-(group,jchunk)
// partial max/min CODES. Also inits the 3 scalars (no reader until reduce1).
template <bool WC>
__global__ __launch_bounds__(256) void k_pass1(const float* __restrict__ x,
                                               const float* __restrict__ scale,
                                               float* __restrict__ fbuf,
                                               char* __restrict__ codes) {
    if (blockIdx.x == 0 && threadIdx.x == 0) {
        fbuf[SC_OFF + 0] = 0.0f;                        // amax_sub (>=0, atomicMax)
        fbuf[SC_OFF + 1] = 0.0f;                        // max_s    (>0, atomicMax)
        fbuf[SC_OFF + 2] = __int_as_float(0x7f800000);  // min_s = +inf (atomicMin)
    }
    const int b  = blockIdx.x / NJC;
    const int jc = blockIdx.x % NJC;
    const int c0 = threadIdx.x * 4;
    const float sinv = 1.0f / scale[0];
    const size_t base = ((size_t)(b * Jdim + jc * JCHUNK)) * Cdim + c0;
    const float* px = x + base;

    float4 vmax = make_float4(-INFINITY, -INFINITY, -INFINITY, -INFINITY);
    float4 vmin = make_float4( INFINITY,  INFINITY,  INFINITY,  INFINITY);
    for (int r = 0; r < JCHUNK; ++r) {
        const float4 v = *reinterpret_cast<const float4*>(px + (size_t)r * Cdim);
        float q0 = code8(v.x, sinv), q1 = code8(v.y, sinv);
        float q2 = code8(v.z, sinv), q3 = code8(v.w, sinv);
        vmax.x = fmaxf(vmax.x, q0); vmin.x = fminf(vmin.x, q0);
        vmax.y = fmaxf(vmax.y, q1); vmin.y = fminf(vmin.y, q1);
        vmax.z = fmaxf(vmax.z, q2); vmin.z = fminf(vmin.z, q2);
        vmax.w = fmaxf(vmax.w, q3); vmin.w = fminf(vmin.w, q3);
        if (WC) {
            char4 pk = make_char4((signed char)(int)q0, (signed char)(int)q1,
                                  (signed char)(int)q2, (signed char)(int)q3);
            *reinterpret_cast<char4*>(codes + base + (size_t)r * Cdim) = pk;
        }
    }
    const size_t pidx = ((size_t)(b * NJC + jc)) * Cdim + c0;
    *reinterpret_cast<float4*>(fbuf + A_OFF + pidx) = vmax;
    *reinterpret_cast<float4*>(fbuf + B_OFF + pidx) = vmin;
}

// Reduce 1: gmax code per group; amax_sub = max_g min(12, gmaxc*s - gminc*s).
// (gmax value == gmaxcode*s with identical rounding to reference's max(xq).)
__global__ __launch_bounds__(256) void k_reduce1(const float* __restrict__ scale,
                                                 float* __restrict__ fbuf) {
    const int g = blockIdx.x * 256 + threadIdx.x;   // 0..8191
    const int b = g / Cdim, c = g % Cdim;
    const float s = scale[0];
    float gmax = -INFINITY, gmin = INFINITY;
    for (int jc = 0; jc < NJC; ++jc) {
        const size_t idx = ((size_t)(b * NJC + jc)) * Cdim + c;
        gmax = fmaxf(gmax, fbuf[A_OFF + idx]);
        gmin = fminf(gmin, fbuf[B_OFF + idx]);
    }
    fbuf[GMAX_OFF + g] = gmax;                       // stored as CODE
    float d = fminf(12.0f, gmax * s - gmin * s);

    __shared__ float red[256];
    red[threadIdx.x] = d;
    __syncthreads();
    for (int off = 128; off; off >>= 1) {
        if (threadIdx.x < off) red[threadIdx.x] = fmaxf(red[threadIdx.x], red[threadIdx.x + off]);
        __syncthreads();
    }
    if (threadIdx.x == 0)
        atomicMax(reinterpret_cast<unsigned int*>(fbuf + SC_OFF + 0), __float_as_uint(red[0]));
}

// Pass 2: partial sums of e_q per (group, jchunk); reads codes (or x fallback).
template <bool UC>
__global__ __launch_bounds__(256) void k_pass2(const float* __restrict__ x,
                                               const char* __restrict__ codes,
                                               const float* __restrict__ scale,
                                               float* __restrict__ fbuf) {
    const int b  = blockIdx.x / NJC;
    const int jc = blockIdx.x % NJC;
    const int c0 = threadIdx.x * 4;
    const float s = scale[0];
    const float sinv = 1.0f / s;
    const float amax = fmaxf(fbuf[SC_OFF + 0], 1e-9f);
    const float ssub = amax / 32767.0f;
    const float ssub_inv = 1.0f / ssub;
    const float4 gmc = *reinterpret_cast<const float4*>(fbuf + GMAX_OFF + b * Cdim + c0);
    const float gm0 = gmc.x * s, gm1 = gmc.y * s, gm2 = gmc.z * s, gm3 = gmc.w * s;
    const size_t base = ((size_t)(b * Jdim + jc * JCHUNK)) * Cdim + c0;

    float4 acc = make_float4(0.f, 0.f, 0.f, 0.f);
    for (int r = 0; r < JCHUNK; ++r) {
        float xq0, xq1, xq2, xq3;
        if (UC) {
            const char4 q = *reinterpret_cast<const char4*>(codes + base + (size_t)r * Cdim);
            xq0 = (float)q.x * s; xq1 = (float)q.y * s;
            xq2 = (float)q.z * s; xq3 = (float)q.w * s;
        } else {
            const float4 v = *reinterpret_cast<const float4*>(x + base + (size_t)r * Cdim);
            xq0 = code8(v.x, sinv) * s; xq1 = code8(v.y, sinv) * s;
            xq2 = code8(v.z, sinv) * s; xq3 = code8(v.w, sinv) * s;
        }
        acc.x += eq_from(xq0, gm0, ssub_inv, ssub);
        acc.y += eq_from(xq1, gm1, ssub_inv, ssub);
        acc.z += eq_from(xq2, gm2, ssub_inv, ssub);
        acc.w += eq_from(xq3, gm3, ssub_inv, ssub);
    }
    const size_t pidx = ((size_t)(b * NJC + jc)) * Cdim + c0;
    *reinterpret_cast<float4*>(fbuf + A_OFF + pidx) = acc;  // reuse bufA
}

// Reduce 2: group sums (fixed order) + global max_s / min_s.
__global__ __launch_bounds__(256) void k_reduce2(float* __restrict__ fbuf) {
    const int g = blockIdx.x * 256 + threadIdx.x;
    const int b = g / Cdim, c = g % Cdim;
    float ssum = 0.0f;
    for (int jc = 0; jc < NJC; ++jc)
        ssum += fbuf[A_OFF + ((size_t)(b * NJC + jc)) * Cdim + c];
    fbuf[S_OFF + g] = ssum;

    __shared__ float rmx[256], rmn[256];
    rmx[threadIdx.x] = ssum; rmn[threadIdx.x] = ssum;
    __syncthreads();
    for (int off = 128; off; off >>= 1) {
        if (threadIdx.x < off) {
            rmx[threadIdx.x] = fmaxf(rmx[threadIdx.x], rmx[threadIdx.x + off]);
            rmn[threadIdx.x] = fminf(rmn[threadIdx.x], rmn[threadIdx.x + off]);
        }
        __syncthreads();
    }
    if (threadIdx.x == 0) {
        atomicMax(reinterpret_cast<unsigned int*>(fbuf + SC_OFF + 1), __float_as_uint(rmx[0]));
        atomicMin(reinterpret_cast<unsigned int*>(fbuf + SC_OFF + 2), __float_as_uint(rmn[0]));
    }
}

// Pass 3: out = fq_auto(e_q * r_q, q8). Scales derived from 3 scalars (fq monotone:
// min s_q = fq(min s); max r = 1/min s_q; max r_q = fq(max r) = max r).
template <bool UC>
__global__ __launch_bounds__(256) void k_pass3(const float* __restrict__ x,
                                               const char* __restrict__ codes,
                                               const float* __restrict__ scale,
                                               const float* __restrict__ fbuf,
                                               float* __restrict__ out) {
    const int b  = blockIdx.x / NJC;
    const int jc = blockIdx.x % NJC;
    const int c0 = threadIdx.x * 4;
    const float s = scale[0];
    const float sinv = 1.0f / s;

    const float amax = fmaxf(fbuf[SC_OFF + 0], 1e-9f);
    const float ssub = amax / 32767.0f;
    const float ssub_inv = 1.0f / ssub;

    const float max_s = fbuf[SC_OFF + 1];
    const float min_s = fbuf[SC_OFF + 2];
    const float scale_s = fmaxf(max_s, 1e-9f) / 32767.0f;
    const float ss_inv = 1.0f / scale_s;
    const float minsq = fminf(fmaxf(rintf(min_s * ss_inv), -32768.0f), 32767.0f) * scale_s;
    const float maxr  = 1.0f / minsq;
    const float scale_r = fmaxf(maxr, 1e-9f) / 32767.0f;
    const float sr_inv  = 1.0f / scale_r;
    const float maxrq = fminf(fmaxf(rintf(maxr * sr_inv), -32768.0f), 32767.0f) * scale_r;
    const float scale_out = fmaxf(maxrq, 1e-9f) / 127.0f;
    const float so_inv = 1.0f / scale_out;

    const float4 gmc = *reinterpret_cast<const float4*>(fbuf + GMAX_OFF + b * Cdim + c0);
    const float gm0 = gmc.x * s, gm1 = gmc.y * s, gm2 = gmc.z * s, gm3 = gmc.w * s;
    const float4 s4 = *reinterpret_cast<const float4*>(fbuf + S_OFF + b * Cdim + c0);

    float4 rq;
    {
        float q0 = fminf(fmaxf(rintf(s4.x * ss_inv), -32768.0f), 32767.0f) * scale_s;
        float q1 = fminf(fmaxf(rintf(s4.y * ss_inv), -32768.0f), 32767.0f) * scale_s;
        float q2 = fminf(fmaxf(rintf(s4.z * ss_inv), -32768.0f), 32767.0f) * scale_s;
        float q3 = fminf(fmaxf(rintf(s4.w * ss_inv), -32768.0f), 32767.0f) * scale_s;
        rq.x = fminf(fmaxf(rintf((1.0f / q0) * sr_inv), -32768.0f), 32767.0f) * scale_r;
        rq.y = fminf(fmaxf(rintf((1.0f / q1) * sr_inv), -32768.0f), 32767.0f) * scale_r;
        rq.z = fminf(fmaxf(rintf((1.0f / q2) * sr_inv), -32768.0f), 32767.0f) * scale_r;
        rq.w = fminf(fmaxf(rintf((1.0f / q3) * sr_inv), -32768.0f), 32767.0f) * scale_r;
    }

    const size_t base = ((size_t)(b * Jdim + jc * JCHUNK)) * Cdim + c0;
    float* po = out + base;
    for (int r = 0; r < JCHUNK; ++r) {
        float xq0, xq1, xq2, xq3;
        if (UC) {
            const char4 q = *reinterpret_cast<const char4*>(codes + base + (size_t)r * Cdim);
            xq0 = (float)q.x * s; xq1 = (float)q.y * s;
            xq2 = (float)q.z * s; xq3 = (float)q.w * s;
        } else {
            const float4 v = *reinterpret_cast<const float4*>(x + base + (size_t)r * Cdim);
            xq0 = code8(v.x, sinv) * s; xq1 = code8(v.y, sinv) * s;
            xq2 = code8(v.z, sinv) * s; xq3 = code8(v.w, sinv) * s;
        }
        float e0 = eq_from(xq0, gm0, ssub_inv, ssub) * rq.x;
        float e1 = eq_from(xq1, gm1, ssub_inv, ssub) * rq.y;
        float e2 = eq_from(xq2, gm2, ssub_inv, ssub) * rq.z;
        float e3 = eq_from(xq3, gm3, ssub_inv, ssub) * rq.w;
        float4 o;
        o.x = fminf(fmaxf(rintf(e0 * so_inv), -128.0f), 127.0f) * scale_out;
        o.y = fminf(fmaxf(rintf(e1 * so_inv), -128.0f), 127.0f) * scale_out;
        o.z = fminf(fmaxf(rintf(e2 * so_inv), -128.0f), 127.0f) * scale_out;
        o.w = fminf(fmaxf(rintf(e3 * so_inv), -128.0f), 127.0f) * scale_out;
        *reinterpret_cast<float4*>(po + (size_t)r * Cdim) = o;
    }
}

extern "C" void kernel_launch(void* const* d_in, const int* in_sizes, int n_in,
                              void* d_out, int out_size, void* d_ws, size_t ws_size,
                              hipStream_t stream) {
    const float* x     = (const float*)d_in[0];
    const float* scale = (const float*)d_in[1];
    float* out = (float*)d_out;

    const bool uc = ws_size >= CODES_BYTES + FREGION_BYTES;  // ~36.3 MB
    char*  codes = uc ? (char*)d_ws : nullptr;
    float* fbuf  = uc ? (float*)((char*)d_ws + CODES_BYTES) : (float*)d_ws;

    if (uc) {
        k_pass1<true ><<<Bdim * NJC, 256, 0, stream>>>(x, scale, fbuf, codes);
        k_reduce1<<<NG / 256, 256, 0, stream>>>(scale, fbuf);
        k_pass2<true ><<<Bdim * NJC, 256, 0, stream>>>(x, codes, scale, fbuf);
        k_reduce2<<<NG / 256, 256, 0, stream>>>(fbuf);
        k_pass3<true ><<<Bdim * NJC, 256, 0, stream>>>(x, codes, scale, fbuf, out);
    } else {
        k_pass1<false><<<Bdim * NJC, 256, 0, stream>>>(x, scale, fbuf, codes);
        k_reduce1<<<NG / 256, 256, 0, stream>>>(scale, fbuf);
        k_pass2<false><<<Bdim * NJC, 256, 0, stream>>>(x, codes, scale, fbuf);
        k_reduce2<<<NG / 256, 256, 0, stream>>>(fbuf);
        k_pass3<false><<<Bdim * NJC, 256, 0, stream>>>(x, codes, scale, fbuf, out);
    }
}

// Round 3
// 101.449 us; speedup vs baseline: 1.2093x; 1.2093x over previous
//
#include <hip/hip_runtime.h>
#include <math.h>

// Quantized softmax over axis 1 of x(8, 4096, 1024) fp32.
// Groups: g = b*1024 + c (8192 groups of 4096, stride 1024 floats).
//
// Structure (3 streaming passes + 2 wide reduces):
//   pass1: x -> int8 codes (32 MiB) + per-(g, jchunk) partial max/min codes
//   reduce1: group max code + global amax_sub = max_g min(12, gmax-gmin)
//   pass2: codes -> partial sums of e_q
//   reduce2: group sums + global max_s/min_s
//   pass3: codes -> out = fq8(e_q * r_q)
// All group-scalar math is derived from 3 global scalars (fq is monotone).
// Codes path is bit-identical to recomputing from x (xq == code*s exactly).

typedef float       f4 __attribute__((ext_vector_type(4)));
typedef signed char c4 __attribute__((ext_vector_type(4)));

static constexpr int Bdim = 8;
static constexpr int Jdim = 4096;
static constexpr int Cdim = 1024;
static constexpr int JCHUNK = 16;                 // rows per block (was 64)
static constexpr int NJC = Jdim / JCHUNK;         // 256 -> grid 2048, 8 blocks/CU
static constexpr int NG = Bdim * Cdim;            // 8192 groups
static constexpr int PSIZE = Bdim * NJC * Cdim;   // 2,097,152 partials

// float-region layout (offsets in floats)
static constexpr int SC_OFF   = 0;                // [0]=amax_sub [1]=max_s [2]=min_s
static constexpr int GMAX_OFF = 16;               // 8192 group max CODES (as float)
static constexpr int S_OFF    = GMAX_OFF + NG;    // 8192 group sums of e_q
static constexpr int PS_OFF   = S_OFF + NG;       // PSIZE partial sums (pass2)
static constexpr size_t FB_FLOATS   = (size_t)PS_OFF + PSIZE;
static constexpr size_t FB_BYTES    = FB_FLOATS * 4;          // ~8.45 MB
static constexpr size_t CODES_BYTES = (size_t)Bdim * Jdim * Cdim;  // 32 MiB
static constexpr size_t P_BYTES     = 2 * (size_t)PSIZE;      // pmax+pmin int8

__device__ __forceinline__ float code8(float x, float sinv) {
    // int8 code as float; rintf = round-half-even matches jnp.round
    return fminf(fmaxf(rintf(x * sinv), -128.0f), 127.0f);
}

// e_q = fq16(exp(fq16(clip(xq - gmax, -12, 0)))); scale_e = 1/32767 exactly
// (group-max element has sub==0 -> e==1 -> absmax(e)==1). The 16-bit clamps
// are provably inactive: |sub| <= amax_sub, e in (0,1].
__device__ __forceinline__ float eq_from(float xq, float gmv, float ssub_inv, float ssub) {
    float sub = fminf(fmaxf(xq - gmv, -12.0f), 0.0f);
    float q   = rintf(sub * ssub_inv);
    float e   = __expf(q * ssub);
    return rintf(e * 32767.0f) * (1.0f / 32767.0f);
}

// Pass 1: read x (nontemporal), write int8 codes + per-(g,jc) partial max/min
// codes (int8). Inits the 3 scalars (no reader until reduce1).
template <bool WC>
__global__ __launch_bounds__(256) void k_pass1(const float* __restrict__ x,
                                               const float* __restrict__ scale,
                                               float* __restrict__ fbuf,
                                               signed char* __restrict__ codes,
                                               signed char* __restrict__ pmax,
                                               signed char* __restrict__ pmin) {
    if (blockIdx.x == 0 && threadIdx.x == 0) {
        fbuf[SC_OFF + 0] = 0.0f;                        // amax_sub (>=0, atomicMax)
        fbuf[SC_OFF + 1] = 0.0f;                        // max_s    (>0, atomicMax)
        fbuf[SC_OFF + 2] = __int_as_float(0x7f800000);  // min_s = +inf (atomicMin)
    }
    const int b  = blockIdx.x / NJC;
    const int jc = blockIdx.x % NJC;
    const int c0 = threadIdx.x * 4;
    const float sinv = 1.0f / scale[0];
    const size_t base = ((size_t)(b * Jdim + jc * JCHUNK)) * Cdim + c0;

    f4 vmax = {-1e30f, -1e30f, -1e30f, -1e30f};
    f4 vmin = { 1e30f,  1e30f,  1e30f,  1e30f};
    #pragma unroll 4
    for (int r = 0; r < JCHUNK; ++r) {
        const f4 v = __builtin_nontemporal_load(
            reinterpret_cast<const f4*>(x + base + (size_t)r * Cdim));
        f4 q;
        q[0] = code8(v[0], sinv); q[1] = code8(v[1], sinv);
        q[2] = code8(v[2], sinv); q[3] = code8(v[3], sinv);
        vmax[0] = fmaxf(vmax[0], q[0]); vmin[0] = fminf(vmin[0], q[0]);
        vmax[1] = fmaxf(vmax[1], q[1]); vmin[1] = fminf(vmin[1], q[1]);
        vmax[2] = fmaxf(vmax[2], q[2]); vmin[2] = fminf(vmin[2], q[2]);
        vmax[3] = fmaxf(vmax[3], q[3]); vmin[3] = fminf(vmin[3], q[3]);
        if (WC) {
            c4 pk = {(signed char)(int)q[0], (signed char)(int)q[1],
                     (signed char)(int)q[2], (signed char)(int)q[3]};
            *reinterpret_cast<c4*>(codes + base + (size_t)r * Cdim) = pk;
        }
    }
    const size_t pidx = ((size_t)(b * NJC + jc)) * Cdim + c0;
    c4 mx = {(signed char)(int)vmax[0], (signed char)(int)vmax[1],
             (signed char)(int)vmax[2], (signed char)(int)vmax[3]};
    c4 mn = {(signed char)(int)vmin[0], (signed char)(int)vmin[1],
             (signed char)(int)vmin[2], (signed char)(int)vmin[3]};
    *reinterpret_cast<c4*>(pmax + pidx) = mx;
    *reinterpret_cast<c4*>(pmin + pidx) = mn;
}

// Reduce 1 (wide: 256 blocks x 256 thr, 8 threads/group + LDS tree).
// Writes group max CODE; atomicMax amax_sub = max_g min(12, fl(gmax*s)-fl(gmin*s)).
__global__ __launch_bounds__(256) void k_reduce1(const float* __restrict__ scale,
                                                 float* __restrict__ fbuf,
                                                 const signed char* __restrict__ pmax,
                                                 const signed char* __restrict__ pmin) {
    const int b   = blockIdx.x / 32;       // 8 batches
    const int ct  = blockIdx.x % 32;       // 32 col-tiles of 32
    const int ci  = threadIdx.x & 31;
    const int sub = threadIdx.x >> 5;      // 0..7
    const int c   = ct * 32 + ci;

    int mx = -128, mn = 127;
    for (int jc = sub; jc < NJC; jc += 8) {
        const size_t idx = ((size_t)(b * NJC + jc)) * Cdim + c;
        mx = max(mx, (int)pmax[idx]);
        mn = min(mn, (int)pmin[idx]);
    }
    __shared__ int smx[8][32], smn[8][32];
    smx[sub][ci] = mx; smn[sub][ci] = mn;
    __syncthreads();
    for (int off = 4; off; off >>= 1) {
        if (sub < off) {
            smx[sub][ci] = max(smx[sub][ci], smx[sub + off][ci]);
            smn[sub][ci] = min(smn[sub][ci], smn[sub + off][ci]);
        }
        __syncthreads();
    }
    __shared__ float sd[32];
    if (sub == 0) {
        const float s = scale[0];
        const float gmaxv = (float)smx[0][ci] * s;   // == reference max(xq)
        const float gminv = (float)smn[0][ci] * s;
        fbuf[GMAX_OFF + b * Cdim + c] = (float)smx[0][ci];
        sd[ci] = fminf(12.0f, gmaxv - gminv);
    }
    __syncthreads();
    if (threadIdx.x == 0) {
        float m = sd[0];
        #pragma unroll
        for (int i = 1; i < 32; ++i) m = fmaxf(m, sd[i]);
        atomicMax(reinterpret_cast<unsigned int*>(fbuf + SC_OFF + 0), __float_as_uint(m));
    }
}

// Pass 2: partial sums of e_q per (g, jc); reads codes (or x fallback).
template <bool UC>
__global__ __launch_bounds__(256) void k_pass2(const float* __restrict__ x,
                                               const signed char* __restrict__ codes,
                                               const float* __restrict__ scale,
                                               float* __restrict__ fbuf) {
    const int b  = blockIdx.x / NJC;
    const int jc = blockIdx.x % NJC;
    const int c0 = threadIdx.x * 4;
    const float s = scale[0];
    const float sinv = 1.0f / s;
    const float amax = fmaxf(fbuf[SC_OFF + 0], 1e-9f);
    const float ssub = amax / 32767.0f;
    const float ssub_inv = 1.0f / ssub;
    const f4 gmc = *reinterpret_cast<const f4*>(fbuf + GMAX_OFF + b * Cdim + c0);
    const float gm0 = gmc[0] * s, gm1 = gmc[1] * s, gm2 = gmc[2] * s, gm3 = gmc[3] * s;
    const size_t base = ((size_t)(b * Jdim + jc * JCHUNK)) * Cdim + c0;

    float a0 = 0.f, a1 = 0.f, a2 = 0.f, a3 = 0.f;
    #pragma unroll 4
    for (int r = 0; r < JCHUNK; ++r) {
        float xq0, xq1, xq2, xq3;
        if (UC) {
            const c4 q = *reinterpret_cast<const c4*>(codes + base + (size_t)r * Cdim);
            xq0 = (float)q[0] * s; xq1 = (float)q[1] * s;
            xq2 = (float)q[2] * s; xq3 = (float)q[3] * s;
        } else {
            const f4 v = *reinterpret_cast<const f4*>(x + base + (size_t)r * Cdim);
            xq0 = code8(v[0], sinv) * s; xq1 = code8(v[1], sinv) * s;
            xq2 = code8(v[2], sinv) * s; xq3 = code8(v[3], sinv) * s;
        }
        a0 += eq_from(xq0, gm0, ssub_inv, ssub);
        a1 += eq_from(xq1, gm1, ssub_inv, ssub);
        a2 += eq_from(xq2, gm2, ssub_inv, ssub);
        a3 += eq_from(xq3, gm3, ssub_inv, ssub);
    }
    f4 acc = {a0, a1, a2, a3};
    *reinterpret_cast<f4*>(fbuf + PS_OFF + ((size_t)(b * NJC + jc)) * Cdim + c0) = acc;
}

// Reduce 2 (wide): group sums (deterministic fixed tree) + global max_s/min_s.
__global__ __launch_bounds__(256) void k_reduce2(float* __restrict__ fbuf) {
    const int b   = blockIdx.x / 32;
    const int ct  = blockIdx.x % 32;
    const int ci  = threadIdx.x & 31;
    const int sub = threadIdx.x >> 5;
    const int c   = ct * 32 + ci;

    float p = 0.0f;
    for (int jc = sub; jc < NJC; jc += 8)
        p += fbuf[PS_OFF + ((size_t)(b * NJC + jc)) * Cdim + c];
    __shared__ float sp[8][32];
    sp[sub][ci] = p;
    __syncthreads();
    for (int off = 4; off; off >>= 1) {
        if (sub < off) sp[sub][ci] += sp[sub + off][ci];
        __syncthreads();
    }
    __shared__ float smx[32], smn[32];
    if (sub == 0) {
        const float t = sp[0][ci];
        fbuf[S_OFF + b * Cdim + c] = t;
        smx[ci] = t; smn[ci] = t;
    }
    __syncthreads();
    if (threadIdx.x == 0) {
        float mx = smx[0], mn = smn[0];
        #pragma unroll
        for (int i = 1; i < 32; ++i) { mx = fmaxf(mx, smx[i]); mn = fminf(mn, smn[i]); }
        atomicMax(reinterpret_cast<unsigned int*>(fbuf + SC_OFF + 1), __float_as_uint(mx));
        atomicMin(reinterpret_cast<unsigned int*>(fbuf + SC_OFF + 2), __float_as_uint(mn));
    }
}

// Pass 3: out = fq_auto(e_q * r_q, q8). Scales derived from 3 scalars (fq
// monotone: min s_q = fq(min s); max r = 1/min s_q; max r_q = fq(max r)).
template <bool UC>
__global__ __launch_bounds__(256) void k_pass3(const float* __restrict__ x,
                                               const signed char* __restrict__ codes,
                                               const float* __restrict__ scale,
                                               const float* __restrict__ fbuf,
                                               float* __restrict__ out) {
    const int b  = blockIdx.x / NJC;
    const int jc = blockIdx.x % NJC;
    const int c0 = threadIdx.x * 4;
    const float s = scale[0];
    const float sinv = 1.0f / s;

    const float amax = fmaxf(fbuf[SC_OFF + 0], 1e-9f);
    const float ssub = amax / 32767.0f;
    const float ssub_inv = 1.0f / ssub;

    const float max_s = fbuf[SC_OFF + 1];
    const float min_s = fbuf[SC_OFF + 2];
    const float scale_s = fmaxf(max_s, 1e-9f) / 32767.0f;
    const float ss_inv = 1.0f / scale_s;
    const float minsq = fminf(fmaxf(rintf(min_s * ss_inv), -32768.0f), 32767.0f) * scale_s;
    const float maxr  = 1.0f / minsq;
    const float scale_r = fmaxf(maxr, 1e-9f) / 32767.0f;
    const float sr_inv  = 1.0f / scale_r;
    const float maxrq = fminf(fmaxf(rintf(maxr * sr_inv), -32768.0f), 32767.0f) * scale_r;
    const float scale_out = fmaxf(maxrq, 1e-9f) / 127.0f;
    const float so_inv = 1.0f / scale_out;

    const f4 gmc = *reinterpret_cast<const f4*>(fbuf + GMAX_OFF + b * Cdim + c0);
    const float gm0 = gmc[0] * s, gm1 = gmc[1] * s, gm2 = gmc[2] * s, gm3 = gmc[3] * s;
    const f4 s4 = *reinterpret_cast<const f4*>(fbuf + S_OFF + b * Cdim + c0);

    f4 rq;
    {
        float q0 = fminf(fmaxf(rintf(s4[0] * ss_inv), -32768.0f), 32767.0f) * scale_s;
        float q1 = fminf(fmaxf(rintf(s4[1] * ss_inv), -32768.0f), 32767.0f) * scale_s;
        float q2 = fminf(fmaxf(rintf(s4[2] * ss_inv), -32768.0f), 32767.0f) * scale_s;
        float q3 = fminf(fmaxf(rintf(s4[3] * ss_inv), -32768.0f), 32767.0f) * scale_s;
        rq[0] = fminf(fmaxf(rintf((1.0f / q0) * sr_inv), -32768.0f), 32767.0f) * scale_r;
        rq[1] = fminf(fmaxf(rintf((1.0f / q1) * sr_inv), -32768.0f), 32767.0f) * scale_r;
        rq[2] = fminf(fmaxf(rintf((1.0f / q2) * sr_inv), -32768.0f), 32767.0f) * scale_r;
        rq[3] = fminf(fmaxf(rintf((1.0f / q3) * sr_inv), -32768.0f), 32767.0f) * scale_r;
    }

    const size_t base = ((size_t)(b * Jdim + jc * JCHUNK)) * Cdim + c0;
    #pragma unroll 4
    for (int r = 0; r < JCHUNK; ++r) {
        float xq0, xq1, xq2, xq3;
        if (UC) {
            const c4 q = *reinterpret_cast<const c4*>(codes + base + (size_t)r * Cdim);
            xq0 = (float)q[0] * s; xq1 = (float)q[1] * s;
            xq2 = (float)q[2] * s; xq3 = (float)q[3] * s;
        } else {
            const f4 v = *reinterpret_cast<const f4*>(x + base + (size_t)r * Cdim);
            xq0 = code8(v[0], sinv) * s; xq1 = code8(v[1], sinv) * s;
            xq2 = code8(v[2], sinv) * s; xq3 = code8(v[3], sinv) * s;
        }
        float e0 = eq_from(xq0, gm0, ssub_inv, ssub) * rq[0];
        float e1 = eq_from(xq1, gm1, ssub_inv, ssub) * rq[1];
        float e2 = eq_from(xq2, gm2, ssub_inv, ssub) * rq[2];
        float e3 = eq_from(xq3, gm3, ssub_inv, ssub) * rq[3];
        f4 o;
        o[0] = fminf(fmaxf(rintf(e0 * so_inv), -128.0f), 127.0f) * scale_out;
        o[1] = fminf(fmaxf(rintf(e1 * so_inv), -128.0f), 127.0f) * scale_out;
        o[2] = fminf(fmaxf(rintf(e2 * so_inv), -128.0f), 127.0f) * scale_out;
        o[3] = fminf(fmaxf(rintf(e3 * so_inv), -128.0f), 127.0f) * scale_out;
        __builtin_nontemporal_store(o, reinterpret_cast<f4*>(out + base + (size_t)r * Cdim));
    }
}

extern "C" void kernel_launch(void* const* d_in, const int* in_sizes, int n_in,
                              void* d_out, int out_size, void* d_ws, size_t ws_size,
                              hipStream_t stream) {
    const float* x     = (const float*)d_in[0];
    const float* scale = (const float*)d_in[1];
    float* out = (float*)d_out;

    const bool uc = ws_size >= CODES_BYTES + FB_BYTES + P_BYTES;  // ~46.2 MB
    signed char* codes = uc ? (signed char*)d_ws : nullptr;
    float* fbuf = uc ? (float*)((char*)d_ws + CODES_BYTES) : (float*)d_ws;
    signed char* pmax = (signed char*)((char*)fbuf + FB_BYTES);
    signed char* pmin = pmax + PSIZE;

    if (uc) {
        k_pass1<true ><<<Bdim * NJC, 256, 0, stream>>>(x, scale, fbuf, codes, pmax, pmin);
        k_reduce1<<<256, 256, 0, stream>>>(scale, fbuf, pmax, pmin);
        k_pass2<true ><<<Bdim * NJC, 256, 0, stream>>>(x, codes, scale, fbuf);
        k_reduce2<<<256, 256, 0, stream>>>(fbuf);
        k_pass3<true ><<<Bdim * NJC, 256, 0, stream>>>(x, codes, scale, fbuf, out);
    } else {
        k_pass1<false><<<Bdim * NJC, 256, 0, stream>>>(x, scale, fbuf, codes, pmax, pmin);
        k_reduce1<<<256, 256, 0, stream>>>(scale, fbuf, pmax, pmin);
        k_pass2<false><<<Bdim * NJC, 256, 0, stream>>>(x, codes, scale, fbuf);
        k_reduce2<<<256, 256, 0, stream>>>(fbuf);
        k_pass3<false><<<Bdim * NJC, 256, 0, stream>>>(x, codes, scale, fbuf, out);
    }
}